// Round 1
// baseline (490.940 us; speedup 1.0000x reference)
//
#include <hip/hip_runtime.h>
#include <hip/hip_bf16.h>

// Problem constants
#define NB   128     // frames
#define NP   4096    // points per frame
#define NGRP 16
#define C1   64
#define C2   128
#define C3   512

typedef __bf16 bf16x8 __attribute__((ext_vector_type(8)));
typedef __bf16 bf16x4 __attribute__((ext_vector_type(4)));
typedef float  f32x4  __attribute__((ext_vector_type(4)));

// ws layout (bytes); total 335872 B
#define WS_W1T_G 0        // [64][32] bf16 (k 0..3 real, 4..31 zero)
#define WS_W1T_L 4096
#define WS_W2T_G 8192     // [128][64] bf16
#define WS_W2T_L 24576
#define WS_W3T_G 40960    // [512][128] bf16
#define WS_W3T_L 172032
#define WS_GMAX  303104   // [16][512] f32

// LDS strides (bf16 elements) — padded for uniform bank spread
#define XA_S  40   // [64][40], k 0..31 used
#define H1_S  72   // [64][72], k 0..63 used
#define H2_S  136  // [64][136], k 0..127 used

__global__ void prep_kernel(const float* __restrict__ Wg1, const float* __restrict__ Wg2,
                            const float* __restrict__ Wg3, const float* __restrict__ Wl1,
                            const float* __restrict__ Wl2, const float* __restrict__ Wl3,
                            float* __restrict__ out, char* __restrict__ ws) {
    int gid = blockIdx.x * blockDim.x + threadIdx.x;   // 0..131071
    // zero the entire z region of out (global half overwritten by gather; local half is atomic target)
    out[gid] = 0.0f;
    float* gmax = (float*)(ws + WS_GMAX);
    if (gid < NGRP * C3) gmax[gid] = 0.0f;
    __bf16* w1tg = (__bf16*)(ws + WS_W1T_G);
    __bf16* w1tl = (__bf16*)(ws + WS_W1T_L);
    __bf16* w2tg = (__bf16*)(ws + WS_W2T_G);
    __bf16* w2tl = (__bf16*)(ws + WS_W2T_L);
    __bf16* w3tg = (__bf16*)(ws + WS_W3T_G);
    __bf16* w3tl = (__bf16*)(ws + WS_W3T_L);
    if (gid < 64 * 32) {   // W1T [ch][k(32 padded)]; W1 is [4][64]
        int ch = gid >> 5, k = gid & 31;
        w1tg[gid] = (k < 4) ? (__bf16)Wg1[k * 64 + ch] : (__bf16)0.0f;
        w1tl[gid] = (k < 4) ? (__bf16)Wl1[k * 64 + ch] : (__bf16)0.0f;
    }
    if (gid < 128 * 64) {  // W2T [ch][k]; W2 is [64][128]
        int ch = gid >> 6, k = gid & 63;
        w2tg[gid] = (__bf16)Wg2[k * 128 + ch];
        w2tl[gid] = (__bf16)Wl2[k * 128 + ch];
    }
    if (gid < 512 * 128) { // W3T [ch][k]; W3 is [128][512]
        int ch = gid >> 7, k = gid & 127;
        w3tg[gid] = (__bf16)Wg3[k * 512 + ch];
        w3tl[gid] = (__bf16)Wl3[k * 512 + ch];
    }
}

// 512 threads = 8 waves. Waves 0-3: global branch; waves 4-7: local branch.
// Block = 1024-point chunk of one frame, 16 iterations of 64 points.
__global__ __launch_bounds__(512, 2) void main_kernel(
    const float* __restrict__ pc, const float* __restrict__ tt, const int* __restrict__ idx,
    const float* __restrict__ bg1, const float* __restrict__ bg2, const float* __restrict__ bg3,
    const float* __restrict__ bl1, const float* __restrict__ bl2, const float* __restrict__ bl3,
    float* __restrict__ out, char* __restrict__ ws) {
    __shared__ __align__(16) char smem[58368];
    __bf16* xa  = (__bf16*)smem;                    // [64][40] bf16 (5120 B)
    __bf16* h1s = (__bf16*)(smem + 5120);           // [2][64][72] (18432 B)
    __bf16* h2s = (__bf16*)(smem + 23552);          // [2][64][136] (34816 B)

    const int tid   = threadIdx.x;
    const int lane  = tid & 63;
    const int wave  = tid >> 6;        // 0..7
    const int branch = wave >> 2;      // 0=global, 1=local
    const int wslot = wave & 3;        // 0..3
    const int quad  = lane >> 4;
    const int l15   = lane & 15;

    const int bid   = blockIdx.x;
    const int frame = bid >> 2;
    const int p0    = (bid & 3) * 1024;

    const __bf16* w1t = (const __bf16*)(ws + (branch ? WS_W1T_L : WS_W1T_G));
    const __bf16* w2t = (const __bf16*)(ws + (branch ? WS_W2T_L : WS_W2T_G));
    const __bf16* w3t = (const __bf16*)(ws + (branch ? WS_W3T_L : WS_W3T_G));
    const float* b1 = branch ? bl1 : bg1;
    const float* b2 = branch ? bl2 : bg2;
    const float* b3 = branch ? bl3 : bg3;

    // one-time: zero xa pad channels k=4..31 (never rewritten)
    if (tid < 64) {
        #pragma unroll
        for (int k = 4; k < 32; ++k) xa[tid * XA_S + k] = (__bf16)0.0f;
    }

    const int ch1 = wslot * 16;    // this wave's L1 output-channel base
    const int ch2 = wslot * 32;    // L2 base
    const int ch3 = wslot * 128;   // L3 base

    // resident weight A-fragments (loop-invariant)
    bf16x8 a1 = *(const bf16x8*)(w1t + (ch1 + l15) * 32 + quad * 8);
    bf16x8 a2[2][2];
    #pragma unroll
    for (int mi = 0; mi < 2; ++mi)
        #pragma unroll
        for (int ks = 0; ks < 2; ++ks)
            a2[mi][ks] = *(const bf16x8*)(w2t + (ch2 + mi * 16 + l15) * 64 + ks * 32 + quad * 8);
    float b1r[4], b2r[2][4];
    #pragma unroll
    for (int r = 0; r < 4; ++r) b1r[r] = b1[ch1 + quad * 4 + r];
    #pragma unroll
    for (int mi = 0; mi < 2; ++mi)
        #pragma unroll
        for (int r = 0; r < 4; ++r) b2r[mi][r] = b2[ch2 + mi * 16 + quad * 4 + r];

    const float tval = tt[frame];
    const f32x4 zf = {0.0f, 0.0f, 0.0f, 0.0f};

    // running max of RAW layer-3 accumulators (bias+relu commute with max)
    f32x4 runmax[8];
    #pragma unroll
    for (int mi = 0; mi < 8; ++mi) runmax[mi] = (f32x4){-1e30f, -1e30f, -1e30f, -1e30f};

    for (int it = 0; it < 16; ++it) {
        // ---- stage x tile (wave 0 only): [64 pts][xyz t] -> xa bf16
        if (tid < 64) {
            int p = p0 + it * 64 + tid;
            const float* pcb = pc + frame * 3 * NP + p;
            bf16x4 v = { (__bf16)pcb[0], (__bf16)pcb[NP], (__bf16)pcb[2 * NP], (__bf16)tval };
            *(bf16x4*)(xa + tid * XA_S) = v;
        }
        __syncthreads();

        // ---- layer 1: h1T[16ch x 64pt] per wave = W1T(16x32) @ xaT(32x64)
        {
            __bf16* h1w = h1s + branch * (64 * H1_S);
            #pragma unroll
            for (int ni = 0; ni < 4; ++ni) {
                bf16x8 xb = *(const bf16x8*)(xa + (ni * 16 + l15) * XA_S + quad * 8);
                f32x4 acc = __builtin_amdgcn_mfma_f32_16x16x32_bf16(a1, xb, zf, 0, 0, 0);
                bf16x4 pk;
                #pragma unroll
                for (int r = 0; r < 4; ++r) pk[r] = (__bf16)fmaxf(acc[r] + b1r[r], 0.0f);
                *(bf16x4*)(h1w + (ni * 16 + l15) * H1_S + ch1 + quad * 4) = pk;
            }
        }
        __syncthreads();

        // ---- layer 2: 32ch x 64pt per wave, K=64
        {
            const __bf16* h1w = h1s + branch * (64 * H1_S);
            __bf16* h2w = h2s + branch * (64 * H2_S);
            f32x4 acc2[2][4];
            #pragma unroll
            for (int ks = 0; ks < 2; ++ks) {
                bf16x8 bh[4];
                #pragma unroll
                for (int ni = 0; ni < 4; ++ni)
                    bh[ni] = *(const bf16x8*)(h1w + (ni * 16 + l15) * H1_S + ks * 32 + quad * 8);
                #pragma unroll
                for (int mi = 0; mi < 2; ++mi)
                    #pragma unroll
                    for (int ni = 0; ni < 4; ++ni)
                        acc2[mi][ni] = __builtin_amdgcn_mfma_f32_16x16x32_bf16(
                            a2[mi][ks], bh[ni], ks ? acc2[mi][ni] : zf, 0, 0, 0);
            }
            #pragma unroll
            for (int mi = 0; mi < 2; ++mi)
                #pragma unroll
                for (int ni = 0; ni < 4; ++ni) {
                    bf16x4 pk;
                    #pragma unroll
                    for (int r = 0; r < 4; ++r) pk[r] = (__bf16)fmaxf(acc2[mi][ni][r] + b2r[mi][r], 0.0f);
                    *(bf16x4*)(h2w + (ni * 16 + l15) * H2_S + ch2 + mi * 16 + quad * 4) = pk;
                }
        }
        __syncthreads();

        // ---- layer 3: 128ch x 64pt per wave, K=128, raw accumulate (no bias/relu yet)
        {
            const __bf16* h2w = h2s + branch * (64 * H2_S);
            f32x4 acc3[8][4];
            #pragma unroll
            for (int ks = 0; ks < 4; ++ks) {
                bf16x8 bh[4];
                #pragma unroll
                for (int ni = 0; ni < 4; ++ni)
                    bh[ni] = *(const bf16x8*)(h2w + (ni * 16 + l15) * H2_S + ks * 32 + quad * 8);
                bf16x8 aw[8];
                #pragma unroll
                for (int mi = 0; mi < 8; ++mi)
                    aw[mi] = *(const bf16x8*)(w3t + (ch3 + mi * 16 + l15) * 128 + ks * 32 + quad * 8);
                #pragma unroll
                for (int mi = 0; mi < 8; ++mi)
                    #pragma unroll
                    for (int ni = 0; ni < 4; ++ni)
                        acc3[mi][ni] = __builtin_amdgcn_mfma_f32_16x16x32_bf16(
                            aw[mi], bh[ni], ks ? acc3[mi][ni] : zf, 0, 0, 0);
            }
            #pragma unroll
            for (int mi = 0; mi < 8; ++mi)
                #pragma unroll
                for (int r = 0; r < 4; ++r) {
                    float m0 = fmaxf(fmaxf(acc3[mi][0][r], acc3[mi][1][r]),
                                     fmaxf(acc3[mi][2][r], acc3[mi][3][r]));
                    runmax[mi][r] = fmaxf(runmax[mi][r], m0);
                }
        }
        // no barrier needed here: next stage-x touches only xa, then syncs
    }

    // ---- finalize: reduce over the 16 point-columns, bias+relu, one atomic per channel
    float* fscr = (float*)smem;   // reuse xa region: [2][512] f32
    __syncthreads();
    #pragma unroll
    for (int mi = 0; mi < 8; ++mi)
        #pragma unroll
        for (int r = 0; r < 4; ++r) {
            float v = runmax[mi][r];
            v = fmaxf(v, __shfl_xor(v, 1));
            v = fmaxf(v, __shfl_xor(v, 2));
            v = fmaxf(v, __shfl_xor(v, 4));
            v = fmaxf(v, __shfl_xor(v, 8));
            if (l15 == 0) {
                int ch = ch3 + mi * 16 + quad * 4 + r;
                fscr[branch * C3 + ch] = fmaxf(v + b3[ch], 0.0f);
            }
        }
    __syncthreads();

    const int g = idx[frame];
    float* gmax = (float*)(ws + WS_GMAX);
    for (int i = tid; i < 2 * C3; i += 512) {
        int br = i >> 9, ch = i & 511;
        unsigned uv = __float_as_uint(fscr[i]);   // relu output >= 0 -> uint order == float order
        if (br == 0) atomicMax((unsigned*)(gmax + g * C3 + ch), uv);
        else         atomicMax((unsigned*)(out + frame * (2 * C3) + C3 + ch), uv);
    }
}

__global__ void gather_kernel(const int* __restrict__ idx, const char* __restrict__ ws,
                              float* __restrict__ out) {
    int i = blockIdx.x * blockDim.x + threadIdx.x;   // 0..65535
    int b = i >> 9, ch = i & 511;
    const float* gmax = (const float*)(ws + WS_GMAX);
    out[b * (2 * C3) + ch] = gmax[idx[b] * C3 + ch];
}

extern "C" void kernel_launch(void* const* d_in, const int* in_sizes, int n_in,
                              void* d_out, int out_size, void* d_ws, size_t ws_size,
                              hipStream_t stream) {
    const float* pc  = (const float*)d_in[0];
    const float* tt  = (const float*)d_in[1];
    const int*   idx = (const int*)d_in[2];
    const float* Wg1 = (const float*)d_in[3];  const float* bg1 = (const float*)d_in[4];
    const float* Wg2 = (const float*)d_in[5];  const float* bg2 = (const float*)d_in[6];
    const float* Wg3 = (const float*)d_in[7];  const float* bg3 = (const float*)d_in[8];
    const float* Wl1 = (const float*)d_in[9];  const float* bl1 = (const float*)d_in[10];
    const float* Wl2 = (const float*)d_in[11]; const float* bl2 = (const float*)d_in[12];
    const float* Wl3 = (const float*)d_in[13]; const float* bl3 = (const float*)d_in[14];
    float* out = (float*)d_out;
    char*  ws  = (char*)d_ws;

    // pc passthrough (output 1), bit-exact
    hipMemcpyAsync(out + NB * 2 * C3, pc, (size_t)NB * 3 * NP * sizeof(float),
                   hipMemcpyDeviceToDevice, stream);
    // weights -> bf16 transposed in ws; zero z region + gmax
    prep_kernel<<<512, 256, 0, stream>>>(Wg1, Wg2, Wg3, Wl1, Wl2, Wl3, out, ws);
    // fused MLP + max kernel: 128 frames x 4 chunks
    main_kernel<<<512, 512, 0, stream>>>(pc, tt, idx, bg1, bg2, bg3, bl1, bl2, bl3, out, ws);
    // broadcast group max back to frames
    gather_kernel<<<256, 256, 0, stream>>>(idx, ws, out);
}

// Round 2
// 232.980 us; speedup vs baseline: 2.1072x; 2.1072x over previous
//
#include <hip/hip_runtime.h>
#include <hip/hip_bf16.h>

// Problem constants
#define NB   128     // frames
#define NP   4096    // points per frame
#define NGRP 16
#define C3   512

typedef __bf16 bf16x8 __attribute__((ext_vector_type(8)));
typedef __bf16 bf16x4 __attribute__((ext_vector_type(4)));
typedef float  f32x4  __attribute__((ext_vector_type(4)));

// ws layout (bytes)
#define WS_W1T_G 0        // [64][32] bf16 (k 0..3 real, rest zero)
#define WS_W1T_L 4096
#define WS_W2T_G 8192     // [128][64] bf16
#define WS_W2T_L 24576
#define WS_W3T_G 40960    // [512][128] bf16
#define WS_W3T_L 172032
#define WS_GMAX  303104   // [16][512] f32

// LDS strides (bf16 elements); both are 8 mod 64 -> b128 lane-starts step 4 banks
#define H1_S 72    // h1 [64][72]
#define H2_S 136   // h2 [256][136]

__global__ void prep_kernel(const float* __restrict__ Wg1, const float* __restrict__ Wg2,
                            const float* __restrict__ Wg3, const float* __restrict__ Wl1,
                            const float* __restrict__ Wl2, const float* __restrict__ Wl3,
                            float* __restrict__ out, char* __restrict__ ws) {
    int gid = blockIdx.x * blockDim.x + threadIdx.x;   // 0..131071
    out[gid] = 0.0f;                                   // zero z region (atomic targets)
    float* gmax = (float*)(ws + WS_GMAX);
    if (gid < NGRP * C3) gmax[gid] = 0.0f;
    __bf16* w1tg = (__bf16*)(ws + WS_W1T_G);
    __bf16* w1tl = (__bf16*)(ws + WS_W1T_L);
    __bf16* w2tg = (__bf16*)(ws + WS_W2T_G);
    __bf16* w2tl = (__bf16*)(ws + WS_W2T_L);
    __bf16* w3tg = (__bf16*)(ws + WS_W3T_G);
    __bf16* w3tl = (__bf16*)(ws + WS_W3T_L);
    if (gid < 64 * 32) {   // W1T [ch][32k]; W1 is [4][64]
        int ch = gid >> 5, k = gid & 31;
        w1tg[gid] = (k < 4) ? (__bf16)Wg1[k * 64 + ch] : (__bf16)0.0f;
        w1tl[gid] = (k < 4) ? (__bf16)Wl1[k * 64 + ch] : (__bf16)0.0f;
    }
    if (gid < 128 * 64) {  // W2T [ch][k]; W2 is [64][128]
        int ch = gid >> 6, k = gid & 63;
        w2tg[gid] = (__bf16)Wg2[k * 128 + ch];
        w2tl[gid] = (__bf16)Wl2[k * 128 + ch];
    }
    if (gid < 512 * 128) { // W3T [ch][k]; W3 is [128][512]
        int ch = gid >> 7, k = gid & 127;
        w3tg[gid] = (__bf16)Wg3[k * 512 + ch];
        w3tl[gid] = (__bf16)Wl3[k * 512 + ch];
    }
}

// Grid: (512 chunks, 2 branches). 512 threads = 8 waves, one branch per block.
// Block owns 1024 points of one frame, processed as 4 macro-tiles of 256 pts.
// Phase 1 (per macro): 4 subtiles of 64 pts -> L1 -> L2 -> h2[256][136] in LDS.
// Phase 2 (per macro): per-wave 64-ch x 256-pt L3 GEMM, W3 slice resident in
// 64 VGPRs, h2 streamed from LDS (4-way mi reuse), barrier-free, raw max into
// runmax regs (bias+relu commute with max, applied once at the end).
__global__ __launch_bounds__(512, 2) void main_kernel(
    const float* __restrict__ pc, const float* __restrict__ tt, const int* __restrict__ idx,
    const float* __restrict__ bg1, const float* __restrict__ bg2, const float* __restrict__ bg3,
    const float* __restrict__ bl1, const float* __restrict__ bl2, const float* __restrict__ bl3,
    float* __restrict__ out, char* __restrict__ ws) {
    __shared__ __align__(16) char smem[78848];
    __bf16* h1 = (__bf16*)smem;              // [64][72]  (9216 B)
    __bf16* h2 = (__bf16*)(smem + 9216);     // [256][136] (69632 B)

    const int tid    = threadIdx.x;
    const int lane   = tid & 63;
    const int wave   = tid >> 6;       // 0..7
    const int quad   = lane >> 4;
    const int l15    = lane & 15;
    const int branch = blockIdx.y;     // 0=global, 1=local
    const int chunk  = blockIdx.x;     // 0..511
    const int frame  = chunk >> 2;
    const int p0     = (chunk & 3) * 1024;

    const __bf16* w1t = (const __bf16*)(ws + (branch ? WS_W1T_L : WS_W1T_G));
    const __bf16* w2t = (const __bf16*)(ws + (branch ? WS_W2T_L : WS_W2T_G));
    const __bf16* w3t = (const __bf16*)(ws + (branch ? WS_W3T_L : WS_W3T_G));
    const float* b1 = branch ? bl1 : bg1;
    const float* b2 = branch ? bl2 : bg2;
    const float* b3 = branch ? bl3 : bg3;

    // L1 job split: wave pair -> point group ni1 (0..3), ch half mi1 (0 or 2)
    const int ni1  = wave >> 1;
    const int mi1  = (wave & 1) * 2;
    const int chb2 = wave * 16;        // L2: 16 ch per wave
    const int ch3  = wave * 64;        // L3: 64 ch per wave

    // resident weight fragments
    bf16x8 a1[2];
    #pragma unroll
    for (int mm = 0; mm < 2; ++mm)
        a1[mm] = *(const bf16x8*)(w1t + ((mi1 + mm) * 16 + l15) * 32 + quad * 8);
    bf16x8 a2[2];
    #pragma unroll
    for (int ks = 0; ks < 2; ++ks)
        a2[ks] = *(const bf16x8*)(w2t + (chb2 + l15) * 64 + ks * 32 + quad * 8);
    bf16x8 aw[4][4];   // 64 VGPRs: 64 ch x K=128
    #pragma unroll
    for (int mi = 0; mi < 4; ++mi)
        #pragma unroll
        for (int ks = 0; ks < 4; ++ks)
            aw[mi][ks] = *(const bf16x8*)(w3t + (ch3 + mi * 16 + l15) * 128 + ks * 32 + quad * 8);

    float b1r[2][4], b2r[4];
    #pragma unroll
    for (int mm = 0; mm < 2; ++mm)
        #pragma unroll
        for (int r = 0; r < 4; ++r) b1r[mm][r] = b1[(mi1 + mm) * 16 + quad * 4 + r];
    #pragma unroll
    for (int r = 0; r < 4; ++r) b2r[r] = b2[chb2 + quad * 4 + r];

    const float tval = tt[frame];
    const f32x4 zf = {0.0f, 0.0f, 0.0f, 0.0f};
    f32x4 runmax[4];
    #pragma unroll
    for (int mi = 0; mi < 4; ++mi) runmax[mi] = (f32x4){-1e30f, -1e30f, -1e30f, -1e30f};

    const float* pcx = pc + (size_t)frame * 3 * NP;

    for (int m = 0; m < 4; ++m) {
        // prefetch this macro's x (only quad 0 feeds the frag; loads hoisted early)
        float xf[4][3];
        const int pb = p0 + m * 256 + ni1 * 16 + l15;
        #pragma unroll
        for (int s = 0; s < 4; ++s) {
            xf[s][0] = pcx[pb + s * 64];
            xf[s][1] = pcx[NP + pb + s * 64];
            xf[s][2] = pcx[2 * NP + pb + s * 64];
        }

        // ---- phase 1: build h2 for 256 pts (4 subtiles of 64)
        #pragma unroll
        for (int s = 0; s < 4; ++s) {
            // L1: B-frag built in registers (k 0..3 real -> quad 0 only)
            bf16x8 xb;
            #pragma unroll
            for (int j = 0; j < 8; ++j) xb[j] = (__bf16)0.0f;
            if (quad == 0) {
                xb[0] = (__bf16)xf[s][0]; xb[1] = (__bf16)xf[s][1];
                xb[2] = (__bf16)xf[s][2]; xb[3] = (__bf16)tval;
            }
            #pragma unroll
            for (int mm = 0; mm < 2; ++mm) {
                f32x4 c = __builtin_amdgcn_mfma_f32_16x16x32_bf16(a1[mm], xb, zf, 0, 0, 0);
                bf16x4 pk;
                #pragma unroll
                for (int r = 0; r < 4; ++r) pk[r] = (__bf16)fmaxf(c[r] + b1r[mm][r], 0.0f);
                *(bf16x4*)(h1 + (ni1 * 16 + l15) * H1_S + (mi1 + mm) * 16 + quad * 4) = pk;
            }
            __syncthreads();
            // L2: 16 ch x 64 pts per wave, K=64
            #pragma unroll
            for (int ni = 0; ni < 4; ++ni) {
                bf16x8 q0 = *(const bf16x8*)(h1 + (ni * 16 + l15) * H1_S + quad * 8);
                bf16x8 q1 = *(const bf16x8*)(h1 + (ni * 16 + l15) * H1_S + 32 + quad * 8);
                f32x4 c = __builtin_amdgcn_mfma_f32_16x16x32_bf16(a2[0], q0, zf, 0, 0, 0);
                c = __builtin_amdgcn_mfma_f32_16x16x32_bf16(a2[1], q1, c, 0, 0, 0);
                bf16x4 pk;
                #pragma unroll
                for (int r = 0; r < 4; ++r) pk[r] = (__bf16)fmaxf(c[r] + b2r[r], 0.0f);
                *(bf16x4*)(h2 + (s * 64 + ni * 16 + l15) * H2_S + chb2 + quad * 4) = pk;
            }
            __syncthreads();
        }

        // ---- phase 2: barrier-free L3 stream, 256 MFMAs/wave
        bf16x8 bh[4], bhn[4];
        #pragma unroll
        for (int ks = 0; ks < 4; ++ks)
            bh[ks] = *(const bf16x8*)(h2 + l15 * H2_S + ks * 32 + quad * 8);
        #pragma unroll 4
        for (int ni = 0; ni < 16; ++ni) {
            const int nin = (ni + 1) & 15;
            #pragma unroll
            for (int ks = 0; ks < 4; ++ks)
                bhn[ks] = *(const bf16x8*)(h2 + (nin * 16 + l15) * H2_S + ks * 32 + quad * 8);
            f32x4 acc[4];
            #pragma unroll
            for (int ks = 0; ks < 4; ++ks)
                #pragma unroll
                for (int mi = 0; mi < 4; ++mi)
                    acc[mi] = __builtin_amdgcn_mfma_f32_16x16x32_bf16(
                        aw[mi][ks], bh[ks], ks ? acc[mi] : zf, 0, 0, 0);
            #pragma unroll
            for (int mi = 0; mi < 4; ++mi)
                #pragma unroll
                for (int r = 0; r < 4; ++r)
                    runmax[mi][r] = fmaxf(runmax[mi][r], acc[mi][r]);
            #pragma unroll
            for (int ks = 0; ks < 4; ++ks) bh[ks] = bhn[ks];
        }
        // next macro's h2 writes are fenced by the L1/L2 barrier of subtile 0
    }

    // ---- finalize: fold over the 16 point columns, bias+relu, one atomic per ch
    const int g = idx[frame];
    float* gmax = (float*)(ws + WS_GMAX);
    unsigned* dst = (branch == 0) ? (unsigned*)(gmax + g * C3)
                                  : (unsigned*)(out + frame * (2 * C3) + C3);
    #pragma unroll
    for (int mi = 0; mi < 4; ++mi) {
        f32x4 v = runmax[mi];
        #pragma unroll
        for (int d = 1; d < 16; d <<= 1) {
            #pragma unroll
            for (int r = 0; r < 4; ++r) v[r] = fmaxf(v[r], __shfl_xor(v[r], d));
        }
        if (l15 == 0) {
            #pragma unroll
            for (int r = 0; r < 4; ++r) {
                int ch = ch3 + mi * 16 + quad * 4 + r;
                float fv = fmaxf(v[r] + b3[ch], 0.0f);
                atomicMax(dst + ch, __float_as_uint(fv));  // relu>=0: uint order == float order
            }
        }
    }
}

__global__ void gather_kernel(const int* __restrict__ idx, const char* __restrict__ ws,
                              float* __restrict__ out) {
    int i = blockIdx.x * blockDim.x + threadIdx.x;   // 0..65535
    int b = i >> 9, ch = i & 511;
    const float* gmax = (const float*)(ws + WS_GMAX);
    out[b * (2 * C3) + ch] = gmax[idx[b] * C3 + ch];
}

extern "C" void kernel_launch(void* const* d_in, const int* in_sizes, int n_in,
                              void* d_out, int out_size, void* d_ws, size_t ws_size,
                              hipStream_t stream) {
    const float* pc  = (const float*)d_in[0];
    const float* tt  = (const float*)d_in[1];
    const int*   idx = (const int*)d_in[2];
    const float* Wg1 = (const float*)d_in[3];  const float* bg1 = (const float*)d_in[4];
    const float* Wg2 = (const float*)d_in[5];  const float* bg2 = (const float*)d_in[6];
    const float* Wg3 = (const float*)d_in[7];  const float* bg3 = (const float*)d_in[8];
    const float* Wl1 = (const float*)d_in[9];  const float* bl1 = (const float*)d_in[10];
    const float* Wl2 = (const float*)d_in[11]; const float* bl2 = (const float*)d_in[12];
    const float* Wl3 = (const float*)d_in[13]; const float* bl3 = (const float*)d_in[14];
    float* out = (float*)d_out;
    char*  ws  = (char*)d_ws;

    // pc passthrough (output 1), bit-exact
    hipMemcpyAsync(out + NB * 2 * C3, pc, (size_t)NB * 3 * NP * sizeof(float),
                   hipMemcpyDeviceToDevice, stream);
    prep_kernel<<<512, 256, 0, stream>>>(Wg1, Wg2, Wg3, Wl1, Wl2, Wl3, out, ws);
    main_kernel<<<dim3(512, 2), 512, 0, stream>>>(pc, tt, idx, bg1, bg2, bg3,
                                                  bl1, bl2, bl3, out, ws);
    gather_kernel<<<256, 256, 0, stream>>>(idx, ws, out);
}

// Round 3
// 228.268 us; speedup vs baseline: 2.1507x; 1.0206x over previous
//
#include <hip/hip_runtime.h>
#include <hip/hip_bf16.h>

// Problem constants
#define NB   128     // frames
#define NP   4096    // points per frame
#define NGRP 16
#define C3   512

typedef __bf16 bf16x8 __attribute__((ext_vector_type(8)));
typedef __bf16 bf16x4 __attribute__((ext_vector_type(4)));
typedef float  f32x4  __attribute__((ext_vector_type(4)));
typedef float  float4v __attribute__((ext_vector_type(4)));

// ws layout (bytes)
#define WS_W1T_G 0        // [64][32] bf16 (k 0..3 real, rest zero)
#define WS_W1T_L 4096
#define WS_W2T_G 8192     // [128][64] bf16
#define WS_W2T_L 24576
#define WS_W3T_G 40960    // [512][128] bf16
#define WS_W3T_L 172032
#define WS_GMAX  303104   // [16][512] f32

__global__ void prep_kernel(const float* __restrict__ Wg1, const float* __restrict__ Wg2,
                            const float* __restrict__ Wg3, const float* __restrict__ Wl1,
                            const float* __restrict__ Wl2, const float* __restrict__ Wl3,
                            const float* __restrict__ pc,
                            float* __restrict__ out, char* __restrict__ ws) {
    int gid = blockIdx.x * blockDim.x + threadIdx.x;   // 0..131071
    out[gid] = 0.0f;                                   // zero z region (atomic targets)
    // pc passthrough: 1572864 floats = 393216 float4 = 131072 threads x 3
    {
        const float4v* src = (const float4v*)pc;
        float4v* dst = (float4v*)(out + NB * 2 * C3);
        #pragma unroll
        for (int j = 0; j < 3; ++j) dst[j * 131072 + gid] = src[j * 131072 + gid];
    }
    float* gmax = (float*)(ws + WS_GMAX);
    if (gid < NGRP * C3) gmax[gid] = 0.0f;
    __bf16* w1tg = (__bf16*)(ws + WS_W1T_G);
    __bf16* w1tl = (__bf16*)(ws + WS_W1T_L);
    __bf16* w2tg = (__bf16*)(ws + WS_W2T_G);
    __bf16* w2tl = (__bf16*)(ws + WS_W2T_L);
    __bf16* w3tg = (__bf16*)(ws + WS_W3T_G);
    __bf16* w3tl = (__bf16*)(ws + WS_W3T_L);
    if (gid < 64 * 32) {   // W1T [ch][32k]; W1 is [4][64]
        int ch = gid >> 5, k = gid & 31;
        w1tg[gid] = (k < 4) ? (__bf16)Wg1[k * 64 + ch] : (__bf16)0.0f;
        w1tl[gid] = (k < 4) ? (__bf16)Wl1[k * 64 + ch] : (__bf16)0.0f;
    }
    if (gid < 128 * 64) {  // W2T [ch][k]; W2 is [64][128]
        int ch = gid >> 6, k = gid & 63;
        w2tg[gid] = (__bf16)Wg2[k * 128 + ch];
        w2tl[gid] = (__bf16)Wl2[k * 128 + ch];
    }
    if (gid < 512 * 128) { // W3T [ch][k]; W3 is [128][512]
        int ch = gid >> 7, k = gid & 127;
        w3tg[gid] = (__bf16)Wg3[k * 512 + ch];
        w3tl[gid] = (__bf16)Wl3[k * 512 + ch];
    }
}

// Grid (512 chunks, 2 branches), 512 threads = 8 waves, one branch per block.
// h1/h2 live in LDS in MFMA-FRAGMENT-CHUNK order: the B-frag read for a
// (point-group, ks) is base + lane*16B -> contiguous, bank-conflict-free.
//   h1f chunk (ni(0..3), ks(0..1), quadK(0..3), l15(0..15)) -> 8 bf16
//       offset = ((ni*2+ks)*4 + quadK)*128 + l15*8          [4096 bf16]
//   h2f chunk (pni(0..15), ks(0..3), quadK(0..3), l15)      [32768 bf16]
//       offset = ((pni*4+ks)*4 + quadK)*128 + l15*8
__global__ __launch_bounds__(512, 2) void main_kernel(
    const float* __restrict__ pc, const float* __restrict__ tt, const int* __restrict__ idx,
    const float* __restrict__ bg1, const float* __restrict__ bg2, const float* __restrict__ bg3,
    const float* __restrict__ bl1, const float* __restrict__ bl2, const float* __restrict__ bl3,
    float* __restrict__ out, char* __restrict__ ws) {
    __shared__ __align__(16) char smem[73728];
    __bf16* h1f = (__bf16*)smem;             // 8192 B
    __bf16* h2f = (__bf16*)(smem + 8192);    // 65536 B

    const int tid    = threadIdx.x;
    const int lane   = tid & 63;
    const int wave   = tid >> 6;       // 0..7
    const int quad   = lane >> 4;
    const int l15    = lane & 15;
    const int branch = blockIdx.y;     // 0=global, 1=local
    const int chunk  = blockIdx.x;     // 0..511
    const int frame  = chunk >> 2;
    const int p0     = (chunk & 3) * 1024;

    const __bf16* w1t = (const __bf16*)(ws + (branch ? WS_W1T_L : WS_W1T_G));
    const __bf16* w2t = (const __bf16*)(ws + (branch ? WS_W2T_L : WS_W2T_G));
    const __bf16* w3t = (const __bf16*)(ws + (branch ? WS_W3T_L : WS_W3T_G));
    const float* b1 = branch ? bl1 : bg1;
    const float* b2 = branch ? bl2 : bg2;
    const float* b3 = branch ? bl3 : bg3;

    // L1 job split: wave -> point group ni1 (0..3), ch half mi1 (0 or 2)
    const int ni1  = wave >> 1;
    const int mi1  = (wave & 1) * 2;
    const int chb2 = wave * 16;        // L2: 16 ch per wave
    const int ch3  = wave * 64;        // L3: 64 ch per wave

    // resident weight fragments
    bf16x8 a1[2];
    #pragma unroll
    for (int mm = 0; mm < 2; ++mm)
        a1[mm] = *(const bf16x8*)(w1t + ((mi1 + mm) * 16 + l15) * 32 + quad * 8);
    bf16x8 a2[2];
    #pragma unroll
    for (int ks = 0; ks < 2; ++ks)
        a2[ks] = *(const bf16x8*)(w2t + (chb2 + l15) * 64 + ks * 32 + quad * 8);
    bf16x8 aw[4][4];   // 64 VGPRs: 64 ch x K=128, loop-invariant
    #pragma unroll
    for (int mi = 0; mi < 4; ++mi)
        #pragma unroll
        for (int ks = 0; ks < 4; ++ks)
            aw[mi][ks] = *(const bf16x8*)(w3t + (ch3 + mi * 16 + l15) * 128 + ks * 32 + quad * 8);

    float b1r[2][4], b2r[4];
    #pragma unroll
    for (int mm = 0; mm < 2; ++mm)
        #pragma unroll
        for (int r = 0; r < 4; ++r) b1r[mm][r] = b1[(mi1 + mm) * 16 + quad * 4 + r];
    #pragma unroll
    for (int r = 0; r < 4; ++r) b2r[r] = b2[chb2 + quad * 4 + r];

    const float tval = tt[frame];
    const f32x4 zf = {0.0f, 0.0f, 0.0f, 0.0f};
    f32x4 runmax[4];
    #pragma unroll
    for (int mi = 0; mi < 4; ++mi) runmax[mi] = (f32x4){-1e30f, -1e30f, -1e30f, -1e30f};

    const float* pcx = pc + (size_t)frame * 3 * NP;

    // h1 write chunk coords for this wave's two 16-ch blocks (mi1+mm)
    // c0 = (mi1+mm)*16 + quad*4:  ks=(mi1+mm)>>1, quadK=((mi1+mm)&1)*2+(quad>>1), j0=(quad&1)*4
    // h2 write chunk coords: c0 = wave*16 + quad*4: ks=wave>>1, quadK=(wave&1)*2+(quad>>1)
    const int w2ks = wave >> 1;
    const int w2qk = (wave & 1) * 2 + (quad >> 1);
    const int j0   = (quad & 1) * 4;

    for (int m = 0; m < 4; ++m) {
        // prefetch this macro's x (only quad 0 feeds the frag)
        float xf[4][3];
        const int pb = p0 + m * 256 + ni1 * 16 + l15;
        #pragma unroll
        for (int s = 0; s < 4; ++s) {
            xf[s][0] = pcx[pb + s * 64];
            xf[s][1] = pcx[NP + pb + s * 64];
            xf[s][2] = pcx[2 * NP + pb + s * 64];
        }

        // ---- phase 1: build h2f for 256 pts (4 subtiles of 64)
        #pragma unroll
        for (int s = 0; s < 4; ++s) {
            bf16x8 xb;
            #pragma unroll
            for (int j = 0; j < 8; ++j) xb[j] = (__bf16)0.0f;
            if (quad == 0) {
                xb[0] = (__bf16)xf[s][0]; xb[1] = (__bf16)xf[s][1];
                xb[2] = (__bf16)xf[s][2]; xb[3] = (__bf16)tval;
            }
            #pragma unroll
            for (int mm = 0; mm < 2; ++mm) {
                f32x4 c = __builtin_amdgcn_mfma_f32_16x16x32_bf16(a1[mm], xb, zf, 0, 0, 0);
                bf16x4 pk;
                #pragma unroll
                for (int r = 0; r < 4; ++r) pk[r] = (__bf16)fmaxf(c[r] + b1r[mm][r], 0.0f);
                const int cks = (mi1 + mm) >> 1;
                const int cqk = ((mi1 + mm) & 1) * 2 + (quad >> 1);
                *(bf16x4*)(h1f + ((ni1 * 2 + cks) * 4 + cqk) * 128 + l15 * 8 + j0) = pk;
            }
            __syncthreads();
            // L2: 16 ch x 64 pts per wave, K=64; B-frag reads are lane-contiguous
            #pragma unroll
            for (int ni = 0; ni < 4; ++ni) {
                bf16x8 q0 = *(const bf16x8*)(h1f + (ni * 2 + 0) * 512 + lane * 8);
                bf16x8 q1 = *(const bf16x8*)(h1f + (ni * 2 + 1) * 512 + lane * 8);
                f32x4 c = __builtin_amdgcn_mfma_f32_16x16x32_bf16(a2[0], q0, zf, 0, 0, 0);
                c = __builtin_amdgcn_mfma_f32_16x16x32_bf16(a2[1], q1, c, 0, 0, 0);
                bf16x4 pk;
                #pragma unroll
                for (int r = 0; r < 4; ++r) pk[r] = (__bf16)fmaxf(c[r] + b2r[r], 0.0f);
                const int pni = s * 4 + ni;
                *(bf16x4*)(h2f + ((pni * 4 + w2ks) * 4 + w2qk) * 128 + l15 * 8 + j0) = pk;
            }
            __syncthreads();
        }

        // ---- phase 2: barrier-free L3 stream, 256 MFMAs/wave, conflict-free reads
        bf16x8 bh[4], bhn[4];
        #pragma unroll
        for (int ks = 0; ks < 4; ++ks)
            bh[ks] = *(const bf16x8*)(h2f + ks * 512 + lane * 8);
        #pragma unroll 4
        for (int ni = 0; ni < 16; ++ni) {
            const int nin = (ni + 1) & 15;
            #pragma unroll
            for (int ks = 0; ks < 4; ++ks)
                bhn[ks] = *(const bf16x8*)(h2f + (nin * 4 + ks) * 512 + lane * 8);
            f32x4 acc[4];
            #pragma unroll
            for (int ks = 0; ks < 4; ++ks)
                #pragma unroll
                for (int mi = 0; mi < 4; ++mi)
                    acc[mi] = __builtin_amdgcn_mfma_f32_16x16x32_bf16(
                        aw[mi][ks], bh[ks], ks ? acc[mi] : zf, 0, 0, 0);
            #pragma unroll
            for (int mi = 0; mi < 4; ++mi)
                #pragma unroll
                for (int r = 0; r < 4; ++r)
                    runmax[mi][r] = fmaxf(runmax[mi][r], acc[mi][r]);
            #pragma unroll
            for (int ks = 0; ks < 4; ++ks) bh[ks] = bhn[ks];
        }
        // next macro's h2f writes are fenced by the subtile-0 barriers
    }

    // ---- finalize: fold over the 16 point columns, bias+relu, one atomic per ch
    const int g = idx[frame];
    float* gmax = (float*)(ws + WS_GMAX);
    unsigned* dst = (branch == 0) ? (unsigned*)(gmax + g * C3)
                                  : (unsigned*)(out + frame * (2 * C3) + C3);
    #pragma unroll
    for (int mi = 0; mi < 4; ++mi) {
        f32x4 v = runmax[mi];
        #pragma unroll
        for (int d = 1; d < 16; d <<= 1) {
            #pragma unroll
            for (int r = 0; r < 4; ++r) v[r] = fmaxf(v[r], __shfl_xor(v[r], d));
        }
        if (l15 == 0) {
            #pragma unroll
            for (int r = 0; r < 4; ++r) {
                int ch = ch3 + mi * 16 + quad * 4 + r;
                float fv = fmaxf(v[r] + b3[ch], 0.0f);
                atomicMax(dst + ch, __float_as_uint(fv));  // relu>=0: uint order == float order
            }
        }
    }
}

__global__ void gather_kernel(const int* __restrict__ idx, const char* __restrict__ ws,
                              float* __restrict__ out) {
    int i = blockIdx.x * blockDim.x + threadIdx.x;   // 0..65535
    int b = i >> 9, ch = i & 511;
    const float* gmax = (const float*)(ws + WS_GMAX);
    out[b * (2 * C3) + ch] = gmax[idx[b] * C3 + ch];
}

extern "C" void kernel_launch(void* const* d_in, const int* in_sizes, int n_in,
                              void* d_out, int out_size, void* d_ws, size_t ws_size,
                              hipStream_t stream) {
    const float* pc  = (const float*)d_in[0];
    const float* tt  = (const float*)d_in[1];
    const int*   idx = (const int*)d_in[2];
    const float* Wg1 = (const float*)d_in[3];  const float* bg1 = (const float*)d_in[4];
    const float* Wg2 = (const float*)d_in[5];  const float* bg2 = (const float*)d_in[6];
    const float* Wg3 = (const float*)d_in[7];  const float* bg3 = (const float*)d_in[8];
    const float* Wl1 = (const float*)d_in[9];  const float* bl1 = (const float*)d_in[10];
    const float* Wl2 = (const float*)d_in[11]; const float* bl2 = (const float*)d_in[12];
    const float* Wl3 = (const float*)d_in[13]; const float* bl3 = (const float*)d_in[14];
    float* out = (float*)d_out;
    char*  ws  = (char*)d_ws;

    // prep: weights->bf16 fragment layout, zero z/gmax, pc passthrough copy
    prep_kernel<<<512, 256, 0, stream>>>(Wg1, Wg2, Wg3, Wl1, Wl2, Wl3, pc, out, ws);
    main_kernel<<<dim3(512, 2), 512, 0, stream>>>(pc, tt, idx, bg1, bg2, bg3,
                                                  bl1, bl2, bl3, out, ws);
    gather_kernel<<<256, 256, 0, stream>>>(idx, ws, out);
}

// Round 4
// 202.247 us; speedup vs baseline: 2.4274x; 1.1287x over previous
//
#include <hip/hip_runtime.h>
#include <hip/hip_bf16.h>

// Problem constants
#define NB   128     // frames
#define NP   4096    // points per frame
#define NGRP 16
#define C3   512

typedef __bf16 bf16x8 __attribute__((ext_vector_type(8)));
typedef __bf16 bf16x4 __attribute__((ext_vector_type(4)));
typedef float  f32x4  __attribute__((ext_vector_type(4)));

// ws layout (bytes) — all weights in MFMA A-fragment chunk order:
// chunk c holds A[m=l15][k=quad*8+j] as elem c*512 + lane*8 + j
#define WS_W1F_G 0        // 4 chunks (64ch x K32, k>=4 zero)
#define WS_W1F_L 4096
#define WS_W2F_G 8192     // 16 chunks (128ch x K64): c = mi*2 + ks
#define WS_W2F_L 24576
#define WS_W3F_G 40960    // 128 chunks (512ch x K128): c = (ch>>4)*4 + (k>>5)
#define WS_W3F_L 172032
#define WS_GMAX  303104   // [16][512] f32 (end 335872)

__global__ __launch_bounds__(256) void prep_kernel(
    const float* __restrict__ Wg1, const float* __restrict__ Wg2, const float* __restrict__ Wg3,
    const float* __restrict__ Wl1, const float* __restrict__ Wl2, const float* __restrict__ Wl3,
    const float* __restrict__ pc, float* __restrict__ out, char* __restrict__ ws) {
    const int t = blockIdx.x, tid = threadIdx.x;
    if (t >= 37) {   // pc passthrough: 384 blocks x 1024 float4 (coalesced)
        const f32x4* src = (const f32x4*)pc;
        f32x4* dst = (f32x4*)(out + NB * 2 * C3);
        int base = (t - 37) * 1024 + tid;
        #pragma unroll
        for (int j = 0; j < 4; ++j) dst[base + j * 256] = src[base + j * 256];
        return;
    }
    if (t == 36) {   // W1 frags (both branches) + gmax zero
        float* gmax = (float*)(ws + WS_GMAX);
        #pragma unroll
        for (int k = 0; k < 32; ++k) gmax[k * 256 + tid] = 0.0f;
        int c = tid >> 6, lane = tid & 63;
        int ch = c * 16 + (lane & 15);
        int kb = (lane >> 4) * 8;
        bf16x8 pg, pl;
        #pragma unroll
        for (int j = 0; j < 8; ++j) {
            int k = kb + j;
            pg[j] = (k < 4) ? (__bf16)Wg1[k * 64 + ch] : (__bf16)0.0f;
            pl[j] = (k < 4) ? (__bf16)Wl1[k * 64 + ch] : (__bf16)0.0f;
        }
        *(bf16x8*)((__bf16*)(ws + WS_W1F_G) + c * 512 + lane * 8) = pg;
        *(bf16x8*)((__bf16*)(ws + WS_W1F_L) + c * 512 + lane * 8) = pl;
        return;
    }
    // W2/W3 transpose-to-fragment tiles via LDS (coalesced both sides)
    __shared__ float tile[64][65];
    const float* src; __bf16* dst; int cBase, mMul, srcStride;
    if (t < 32) {       // W3 [128k][512ch]: tiles 64x64, (tk 0..1, tc 0..7) per branch
        int branch = t >> 4, rem = t & 15;
        int tk = rem >> 3, tc = rem & 7;
        src = (branch ? Wl3 : Wg3) + (size_t)(tk * 64) * 512 + tc * 64;
        dst = (__bf16*)(ws + (branch ? WS_W3F_L : WS_W3F_G));
        cBase = tc * 16 + tk * 2; mMul = 4; srcStride = 512;
    } else {            // W2 [64k][128ch]: tiles 64x64, tc 0..1 per branch
        int u = t - 32; int branch = u >> 1, tc = u & 1;
        src = (branch ? Wl2 : Wg2) + tc * 64;
        dst = (__bf16*)(ws + (branch ? WS_W2F_L : WS_W2F_G));
        cBase = tc * 8; mMul = 2; srcStride = 128;
    }
    {
        int r0 = tid >> 6, cl = tid & 63;
        #pragma unroll
        for (int p = 0; p < 16; ++p)
            tile[p * 4 + r0][cl] = src[(size_t)(p * 4 + r0) * srcStride + cl];
    }
    __syncthreads();
    int lane = tid & 63, l15 = lane & 15, q = lane >> 4;
    #pragma unroll
    for (int cc = 0; cc < 2; ++cc) {
        int pair = (tid >> 6) * 2 + cc;     // (mi,ks) 0..7
        int mi = pair >> 1, ks = pair & 1;
        bf16x8 pk;
        #pragma unroll
        for (int j = 0; j < 8; ++j) pk[j] = (__bf16)tile[ks * 32 + q * 8 + j][mi * 16 + l15];
        *(bf16x8*)(dst + (cBase + mi * mMul + ks) * 512 + lane * 8) = pk;
    }
}

// Grid (128 frames, 2 branches) = 256 blocks = 1/CU. 8 waves. Block owns a
// whole frame: 32 macros of 128 pts. Per macro: each wave builds L1+L2 for
// ITS OWN 16 pts (no cross-wave deps, private scratch, no barrier), writes
// h2 frags to double-buffered h2f; ONE barrier; phase-2 streams 128 MFMAs
// per wave with W3 register-resident. P1(m+1) is software-pipelined into
// P2(m) at ni=2/4/6. bias3+relu commute with max -> applied once at end.
__global__ __launch_bounds__(512, 2) void main_kernel(
    const float* __restrict__ pc, const float* __restrict__ tt, const int* __restrict__ idx,
    const float* __restrict__ bg1, const float* __restrict__ bg2, const float* __restrict__ bg3,
    const float* __restrict__ bl1, const float* __restrict__ bl2, const float* __restrict__ bl3,
    float* __restrict__ out, char* __restrict__ ws) {
    __shared__ __align__(16) char smem[102912];
    __bf16* h2f = (__bf16*)smem;               // 2 x 16384 elems (65536 B)
    __bf16* w2f = (__bf16*)(smem + 65536);     // 8192 elems (16384 B)
    __bf16* h1s = (__bf16*)(smem + 81920);     // 8 waves x [16pt][80] (20480 B)
    float*  b2s = (float*)(smem + 102400);     // 128 f32 (512 B)

    const int tid = threadIdx.x, lane = tid & 63, wave = tid >> 6;
    const int quad = lane >> 4, l15 = lane & 15;
    const int branch = blockIdx.y, frame = blockIdx.x;

    const __bf16* w1g = (const __bf16*)(ws + (branch ? WS_W1F_L : WS_W1F_G));
    const __bf16* w2g = (const __bf16*)(ws + (branch ? WS_W2F_L : WS_W2F_G));
    const __bf16* w3g = (const __bf16*)(ws + (branch ? WS_W3F_L : WS_W3F_G));
    const float* b1 = branch ? bl1 : bg1;
    const float* b2 = branch ? bl2 : bg2;
    const float* b3 = branch ? bl3 : bg3;

    // stage W2 frags + b2 into LDS
    for (int i = tid; i < 1024; i += 512) ((f32x4*)w2f)[i] = ((const f32x4*)w2g)[i];
    if (tid < 128) b2s[tid] = b2[tid];

    // resident frags: W1 (16 VGPR), W3 slice (64 VGPR)
    bf16x8 a1[4];
    #pragma unroll
    for (int mi = 0; mi < 4; ++mi) a1[mi] = *(const bf16x8*)(w1g + mi * 512 + lane * 8);
    bf16x8 aw[4][4];
    #pragma unroll
    for (int mi = 0; mi < 4; ++mi)
        #pragma unroll
        for (int ks = 0; ks < 4; ++ks)
            aw[mi][ks] = *(const bf16x8*)(w3g + (wave * 16 + mi * 4 + ks) * 512 + lane * 8);

    float b1r[4][4];
    #pragma unroll
    for (int mi = 0; mi < 4; ++mi)
        #pragma unroll
        for (int r = 0; r < 4; ++r) b1r[mi][r] = b1[mi * 16 + quad * 4 + r];

    const float tval = tt[frame];
    const f32x4 zf = {0.0f, 0.0f, 0.0f, 0.0f};
    f32x4 runmax[4];
    #pragma unroll
    for (int mi = 0; mi < 4; ++mi) runmax[mi] = (f32x4){-1e30f, -1e30f, -1e30f, -1e30f};

    const float* pcx = pc + (size_t)frame * 3 * NP;
    __bf16* hs = h1s + wave * 1280;      // private [16][80] scratch
    const int pw = wave * 16 + l15;      // this wave's point (col l15) in a macro

    // macro-0 x
    float xx = pcx[pw], xy = pcx[NP + pw], xz = pcx[2 * NP + pw];

    __syncthreads();   // w2f/b2s ready

    // ---- prologue: P1(0) -> buf 0
    {
        bf16x8 xb;
        #pragma unroll
        for (int j = 0; j < 8; ++j) xb[j] = (__bf16)0.0f;
        if (quad == 0) { xb[0] = (__bf16)xx; xb[1] = (__bf16)xy; xb[2] = (__bf16)xz; xb[3] = (__bf16)tval; }
        #pragma unroll
        for (int mi = 0; mi < 4; ++mi) {
            f32x4 c = __builtin_amdgcn_mfma_f32_16x16x32_bf16(a1[mi], xb, zf, 0, 0, 0);
            bf16x4 pk;
            #pragma unroll
            for (int r = 0; r < 4; ++r) pk[r] = (__bf16)fmaxf(c[r] + b1r[mi][r], 0.0f);
            *(bf16x4*)(hs + l15 * 80 + mi * 16 + quad * 4) = pk;
        }
        bf16x8 hbf0 = *(const bf16x8*)(hs + l15 * 80 + quad * 8);
        bf16x8 hbf1 = *(const bf16x8*)(hs + l15 * 80 + 32 + quad * 8);
        #pragma unroll
        for (int mi = 0; mi < 8; ++mi) {
            bf16x8 a20 = *(const bf16x8*)(w2f + (mi * 2) * 512 + lane * 8);
            bf16x8 a21 = *(const bf16x8*)(w2f + (mi * 2 + 1) * 512 + lane * 8);
            f32x4 c = __builtin_amdgcn_mfma_f32_16x16x32_bf16(a20, hbf0, zf, 0, 0, 0);
            c = __builtin_amdgcn_mfma_f32_16x16x32_bf16(a21, hbf1, c, 0, 0, 0);
            f32x4 bb = *(const f32x4*)(b2s + mi * 16 + quad * 4);
            bf16x4 pk;
            #pragma unroll
            for (int r = 0; r < 4; ++r) pk[r] = (__bf16)fmaxf(c[r] + bb[r], 0.0f);
            const int c0 = mi * 16 + quad * 4;
            *(bf16x4*)(h2f + ((wave * 4 + (c0 >> 5)) * 4 + ((c0 >> 3) & 3)) * 128 + l15 * 8 + (c0 & 7)) = pk;
        }
    }

    for (int m = 0; m < 32; ++m) {
        __syncthreads();   // h2f buf[m&1] ready (prologue or previous stage C)
        const __bf16* hb = h2f + (m & 1) * 16384;
        __bf16* hbn = h2f + ((m + 1) & 1) * 16384;
        const bool more = (m < 31);
        // prefetch next macro's x early (covered by >=2 ni-groups of MFMA)
        float nx = 0.f, ny = 0.f, nz = 0.f;
        if (more) {
            const int p = (m + 1) * 128 + pw;
            nx = pcx[p]; ny = pcx[NP + p]; nz = pcx[2 * NP + p];
        }
        bf16x8 hbf0, hbf1;
        bf16x8 bh0[4], bh1[4];
        #pragma unroll
        for (int ks = 0; ks < 4; ++ks) bh0[ks] = *(const bf16x8*)(hb + ks * 512 + lane * 8);
        #pragma unroll
        for (int ni = 0; ni < 8; ++ni) {
            bf16x8* cur = (ni & 1) ? bh1 : bh0;
            bf16x8* nxt = (ni & 1) ? bh0 : bh1;
            if (ni < 7) {
                #pragma unroll
                for (int ks = 0; ks < 4; ++ks)
                    nxt[ks] = *(const bf16x8*)(hb + ((ni + 1) * 4 + ks) * 512 + lane * 8);
            }
            f32x4 acc[4];
            #pragma unroll
            for (int ks = 0; ks < 4; ++ks)
                #pragma unroll
                for (int mi = 0; mi < 4; ++mi)
                    acc[mi] = __builtin_amdgcn_mfma_f32_16x16x32_bf16(
                        aw[mi][ks], cur[ks], ks ? acc[mi] : zf, 0, 0, 0);
            #pragma unroll
            for (int mi = 0; mi < 4; ++mi)
                #pragma unroll
                for (int r = 0; r < 4; ++r)
                    runmax[mi][r] = fmaxf(runmax[mi][r], acc[mi][r]);

            if (more && ni == 2) {   // P1 stage A: L1 of macro m+1, private scratch
                bf16x8 xb;
                #pragma unroll
                for (int j = 0; j < 8; ++j) xb[j] = (__bf16)0.0f;
                if (quad == 0) { xb[0] = (__bf16)nx; xb[1] = (__bf16)ny; xb[2] = (__bf16)nz; xb[3] = (__bf16)tval; }
                #pragma unroll
                for (int mi = 0; mi < 4; ++mi) {
                    f32x4 c = __builtin_amdgcn_mfma_f32_16x16x32_bf16(a1[mi], xb, zf, 0, 0, 0);
                    bf16x4 pk;
                    #pragma unroll
                    for (int r = 0; r < 4; ++r) pk[r] = (__bf16)fmaxf(c[r] + b1r[mi][r], 0.0f);
                    *(bf16x4*)(hs + l15 * 80 + mi * 16 + quad * 4) = pk;
                }
            }
            if (more && ni == 4) {   // stage B: C->B transform readback
                hbf0 = *(const bf16x8*)(hs + l15 * 80 + quad * 8);
                hbf1 = *(const bf16x8*)(hs + l15 * 80 + 32 + quad * 8);
            }
            if (more && ni == 6) {   // stage C: L2 -> write next h2f buffer
                #pragma unroll
                for (int mi = 0; mi < 8; ++mi) {
                    bf16x8 a20 = *(const bf16x8*)(w2f + (mi * 2) * 512 + lane * 8);
                    bf16x8 a21 = *(const bf16x8*)(w2f + (mi * 2 + 1) * 512 + lane * 8);
                    f32x4 c = __builtin_amdgcn_mfma_f32_16x16x32_bf16(a20, hbf0, zf, 0, 0, 0);
                    c = __builtin_amdgcn_mfma_f32_16x16x32_bf16(a21, hbf1, c, 0, 0, 0);
                    f32x4 bb = *(const f32x4*)(b2s + mi * 16 + quad * 4);
                    bf16x4 pk;
                    #pragma unroll
                    for (int r = 0; r < 4; ++r) pk[r] = (__bf16)fmaxf(c[r] + bb[r], 0.0f);
                    const int c0 = mi * 16 + quad * 4;
                    *(bf16x4*)(hbn + ((wave * 4 + (c0 >> 5)) * 4 + ((c0 >> 3) & 3)) * 128 + l15 * 8 + (c0 & 7)) = pk;
                }
            }
        }
    }

    // ---- finalize: fold 16 point-columns, bias3+relu, store/atomic
    const int g = idx[frame];
    float* gmax = (float*)(ws + WS_GMAX);
    #pragma unroll
    for (int mi = 0; mi < 4; ++mi) {
        f32x4 v = runmax[mi];
        #pragma unroll
        for (int d = 1; d < 16; d <<= 1) {
            #pragma unroll
            for (int r = 0; r < 4; ++r) v[r] = fmaxf(v[r], __shfl_xor(v[r], d));
        }
        if (l15 == 0) {
            #pragma unroll
            for (int r = 0; r < 4; ++r) {
                const int ch = wave * 64 + mi * 16 + quad * 4 + r;
                const float fv = fmaxf(v[r] + b3[ch], 0.0f);
                if (branch == 0)
                    atomicMax((unsigned*)(gmax + g * C3 + ch), __float_as_uint(fv)); // relu>=0
                else
                    out[(size_t)frame * (2 * C3) + C3 + ch] = fv;  // block owns whole frame
            }
        }
    }
}

__global__ void gather_kernel(const int* __restrict__ idx, const char* __restrict__ ws,
                              float* __restrict__ out) {
    int i = blockIdx.x * blockDim.x + threadIdx.x;   // 0..65535
    int b = i >> 9, ch = i & 511;
    const float* gmax = (const float*)(ws + WS_GMAX);
    out[b * (2 * C3) + ch] = gmax[idx[b] * C3 + ch];
}

extern "C" void kernel_launch(void* const* d_in, const int* in_sizes, int n_in,
                              void* d_out, int out_size, void* d_ws, size_t ws_size,
                              hipStream_t stream) {
    const float* pc  = (const float*)d_in[0];
    const float* tt  = (const float*)d_in[1];
    const int*   idx = (const int*)d_in[2];
    const float* Wg1 = (const float*)d_in[3];  const float* bg1 = (const float*)d_in[4];
    const float* Wg2 = (const float*)d_in[5];  const float* bg2 = (const float*)d_in[6];
    const float* Wg3 = (const float*)d_in[7];  const float* bg3 = (const float*)d_in[8];
    const float* Wl1 = (const float*)d_in[9];  const float* bl1 = (const float*)d_in[10];
    const float* Wl2 = (const float*)d_in[11]; const float* bl2 = (const float*)d_in[12];
    const float* Wl3 = (const float*)d_in[13]; const float* bl3 = (const float*)d_in[14];
    float* out = (float*)d_out;
    char*  ws  = (char*)d_ws;

    // prep: weight frag layout (LDS transpose), gmax zero, pc passthrough
    prep_kernel<<<421, 256, 0, stream>>>(Wg1, Wg2, Wg3, Wl1, Wl2, Wl3, pc, out, ws);
    // main: 128 frames x 2 branches = 256 blocks = 1 per CU
    main_kernel<<<dim3(128, 2), 512, 0, stream>>>(pc, tt, idx, bg1, bg2, bg3,
                                                  bl1, bl2, bl3, out, ws);
    gather_kernel<<<256, 256, 0, stream>>>(idx, ws, out);
}